// Round 9
// baseline (1917.786 us; speedup 1.0000x reference)
//
#include <hip/hip_runtime.h>

// Problem constants
#define B_ 8
#define C_ 128
#define HW_ 512
#define PS 16
#define E_ 16
#define NP 1024   // patches per batch (32x32)
#define FD 512
#define CH_STRIDE (HW_ * HW_)   // x channel stride in floats
#define LROW 260  // padded LDS row (floats); GLOAD writes first 256 (1024B)

// d_out layout (flat f32):
// [0, 131072)        gates   [B, NP, E]
// [131072, 163840)   top_k_indices as float [B, NP, 4]
// [163840, 196608)   top_k_values [B, NP, 4]
// [196608]           aux_loss (0.0f)
//
// d_ws layout: [0,1024) freqf (128 f32 + pad) ; [1024, 1024+2MB) wT

__global__ void freq_kernel(const float* __restrict__ femb,
                            const float* __restrict__ fw,
                            float* __restrict__ freqf,
                            float* __restrict__ out) {
    int t = threadIdx.x;
    if (t == 0) out[196608] = 0.0f;  // aux_loss, rewritten every launch
    if (t < 128) {
        int b = t >> 4, e = t & 15;
        const float* fe = femb + b * FD;
        const float* w  = fw + e * FD;
        double s = 0.0;
        for (int i = 0; i < FD; ++i)
            s = fma((double)fe[i], (double)w[i], s);
        freqf[t] = (float)s;
    }
}

// conv_w [E][C][256] -> wT [C][64][E] in float4 units (exact copy):
// wT4[(c*64 + r4)*16 + e] = cw4[e*8192 + c*64 + r4],  r4 = p*4+qg.
__global__ __launch_bounds__(256) void transpose_w_kernel(
    const float* __restrict__ cw, float* __restrict__ wT) {
  const int tid = blockIdx.x * 256 + threadIdx.x;   // 131072 float4s
  const int e  = tid >> 13;
  const int c  = (tid >> 6) & 127;
  const int r4 = tid & 63;
  const float4 v = reinterpret_cast<const float4*>(cw)[tid];
  reinterpret_cast<float4*>(wT)[(c * 64 + r4) * 16 + e] = v;
}

#define MAC4(XF, WF)                                        \
    acc = __fadd_rn(acc, __fmul_rn((XF).x, (WF).x));        \
    acc = __fadd_rn(acc, __fmul_rn((XF).y, (WF).y));        \
    acc = __fadd_rn(acc, __fmul_rn((XF).z, (WF).z));        \
    acc = __fadd_rn(acc, __fmul_rn((XF).w, (WF).w));

// direct global -> LDS, 16B per lane; LDS dest = uniform base + lane*16
#define GLOAD_LDS(GSRC, LDST)                                                  \
  __builtin_amdgcn_global_load_lds(                                            \
      (const __attribute__((address_space(1))) void*)(GSRC),                   \
      (__attribute__((address_space(3))) void*)(LDST), 16, 0, 0)

// x-row operands (LDS) into rotation slot XA; compile-time indices
#define LDX(XA, P)                                                             \
  XA[0] = *reinterpret_cast<const float4*>(xsc + (P) * LROW + lp16 +  0);      \
  XA[1] = *reinterpret_cast<const float4*>(xsc + (P) * LROW + lp16 +  4);      \
  XA[2] = *reinterpret_cast<const float4*>(xsc + (P) * LROW + lp16 +  8);      \
  XA[3] = *reinterpret_cast<const float4*>(xsc + (P) * LROW + lp16 + 12);

// w-row operands (global, transposed layout) into rotation slot WA
#define LDW(WA, P)                                                             \
  WA[0] = wc4[(P) * 64 +  0];                                                  \
  WA[1] = wc4[(P) * 64 + 16];                                                  \
  WA[2] = wc4[(P) * 64 + 32];                                                  \
  WA[3] = wc4[(P) * 64 + 48];

#define MACSLOT(XA, WA)                                                        \
  MAC4(XA[0], WA[0]); MAC4(XA[1], WA[1]);                                      \
  MAC4(XA[2], WA[2]); MAC4(XA[3], WA[3]);

// one p-step, SCHEDULER-PINNED: loads for p+2 issued, then a hard
// sched_barrier, then MAC(p). The scheduler cannot sink the loads across
// the barrier, so operands are structurally 2 steps (~256 cyc) ahead.
#define STEP(P, XU, WU, XL, WL)                                                \
  { if ((P) < 14) { LDW(WL, (P) + 2) LDX(XL, (P) + 2) }                        \
    __builtin_amdgcn_sched_barrier(0);                                         \
    MACSLOT(XU, WU)                                                            \
    __builtin_amdgcn_sched_barrier(0); }

// Strict sequential f32 mul-then-add per (patch, expert) logit in np order
// (c outer, p, q innermost) -- rounding identical to rounds 3/5/7/8.
// x: GLOAD double-buffered LDS (HBM latency hidden channel-deep), 3-slot
//    depth-2 register rotation.  w: global float4 from transposed wT
//    (L1/L2-hot, 16 e-lanes read 256B contiguous), 3-slot depth-2 rotation.
// All rotation load clusters pinned with sched_barrier(0).
__global__ __launch_bounds__(256, 1) void patch_route_kernel(
    const float* __restrict__ x,
    const float* __restrict__ noise,
    const float* __restrict__ conv_w,
    const float* __restrict__ conv_b,
    const float* __restrict__ freqf,
    const float* __restrict__ wT,
    float* __restrict__ out) {

  __shared__ float xs[2][16][LROW];   // [buf][pixel row p][256 + pad] ~32.5 KB
  __shared__ float slg[16][16];

  const int blk = blockIdx.x;     // 0..511
  const int b   = blk >> 6;
  const int pg  = blk & 63;       // patch group of 16
  const int t   = threadIdx.x;
  const int lp  = t >> 4;         // local patch 0..15
  const int e   = t & 15;         // expert
  const int lp16 = lp * 16;
  const int patch = pg * 16 + lp;        // 0..1023
  const int pi = pg >> 1;                // patch row
  const int wv   = t >> 6;               // wave 0..3
  const int lane = t & 63;

  // block x base: batch b, channel 0, pixel row pi*16, col (pg&1)*256
  const float* xblk = x + (size_t)b * (C_ * CH_STRIDE)
                        + (size_t)(pi * PS) * HW_ + (pg & 1) * 256;

  // per-thread w base in transposed layout (advances 1024 float4 / channel)
  const float4* wc4 = reinterpret_cast<const float4*>(wT) + e;

  // ---- prologue: stage channel 0 (4 GLOADs/wave) + first two w-groups ----
  #pragma unroll
  for (int r = 0; r < 4; ++r) {
    const int p = wv * 4 + r;
    GLOAD_LDS(xblk + p * HW_ + lane * 4, &xs[0][p][0]);
  }
  float4 w0[4], w1[4], w2[4];
  LDW(w0, 0)
  LDW(w1, 1)

  float acc = 0.0f;
  for (int c = 0; c < C_; ++c) {
    const int cur = c & 1;
    asm volatile("s_waitcnt vmcnt(0)" ::: "memory");  // x staged + w0/w1 landed
    __builtin_amdgcn_s_barrier();                     // all waves done w/ buf^1
    __builtin_amdgcn_sched_barrier(0);

    if (c + 1 < C_) {   // stage c+1 into buf^1; lands during MAC phase
      const float* xc = xblk + (size_t)(c + 1) * CH_STRIDE;
      #pragma unroll
      for (int r = 0; r < 4; ++r) {
        const int p = wv * 4 + r;
        GLOAD_LDS(xc + p * HW_ + lane * 4, &xs[cur ^ 1][p][0]);
      }
    }

    const float* xsc = &xs[cur][0][0];
    float4 x0[4], x1[4], x2[4];
    LDX(x0, 0)
    LDX(x1, 1)
    __builtin_amdgcn_sched_barrier(0);

    STEP( 0, x0, w0, x2, w2)
    STEP( 1, x1, w1, x0, w0)
    STEP( 2, x2, w2, x1, w1)
    STEP( 3, x0, w0, x2, w2)
    STEP( 4, x1, w1, x0, w0)
    STEP( 5, x2, w2, x1, w1)
    STEP( 6, x0, w0, x2, w2)
    STEP( 7, x1, w1, x0, w0)
    STEP( 8, x2, w2, x1, w1)
    STEP( 9, x0, w0, x2, w2)
    STEP(10, x1, w1, x0, w0)
    STEP(11, x2, w2, x1, w1)
    STEP(12, x0, w0, x2, w2)
    STEP(13, x1, w1, x0, w0)
    STEP(14, x2, w2, x0, w0)   // no loads (P>=14 guard)
    STEP(15, x0, w0, x1, w1)   // no loads

    wc4 += 1024;               // next channel's w slice
    if (c + 1 < C_) {          // tail-prefetch next channel's w0/w1; the
      LDW(w0, 0)               // loop-top vmcnt(0)+barrier absorbs their latency
      LDW(w1, 1)
    }
    // no closing barrier: buf `cur` is only overwritten at iter c+1's stage,
    // which is after the iter-c+1 barrier (all waves past this MAC by then)
  }

  // logits, f32 adds in reference order: (+conv_b) -> (+freq) -> (+noise)
  float lg = __fadd_rn(acc, conv_b[e]);
  lg = __fadd_rn(lg, freqf[b * 16 + e]);
  lg = __fadd_rn(lg, noise[((size_t)b * NP + patch) * 16 + e]);

  slg[lp][e] = lg;
  __syncthreads();

  // ---- f32 softmax + top-4, one thread per patch (identical to round 3) ----
  if (t < 16) {
    const int pp = t;
    const int pat = pg * 16 + pp;
    float v[16];
    #pragma unroll
    for (int i = 0; i < 16; ++i) v[i] = slg[pp][i];

    float m = v[0];
    #pragma unroll
    for (int i = 1; i < 16; ++i) m = fmaxf(m, v[i]);

    float ex[16];
    #pragma unroll
    for (int i = 0; i < 16; ++i) ex[i] = expf(v[i] - m);

    // numpy pairwise-16 sum for the denominator
    float r[8];
    #pragma unroll
    for (int j = 0; j < 8; ++j) r[j] = __fadd_rn(ex[j], ex[j + 8]);
    float d0 = __fadd_rn(__fadd_rn(r[0], r[1]), __fadd_rn(r[2], r[3]));
    float d1 = __fadd_rn(__fadd_rn(r[4], r[5]), __fadd_rn(r[6], r[7]));
    float den = __fadd_rn(d0, d1);

    float s[16];
    #pragma unroll
    for (int i = 0; i < 16; ++i) s[i] = ex[i] / den;

    unsigned mask = 0;
    int bidx[4]; float bval[4];
    #pragma unroll
    for (int j = 0; j < 4; ++j) {
      int bi = 0; float bv = -1.0f;
      #pragma unroll
      for (int i = 0; i < 16; ++i) {
        if (!((mask >> i) & 1u) && s[i] > bv) { bv = s[i]; bi = i; }
      }
      mask |= 1u << bi;
      bidx[j] = bi; bval[j] = bv;
    }

    const size_t po = (size_t)b * NP + pat;
    float* gout = out + po * 16;
    float* iout = out + 131072 + po * 4;
    float* vout = out + 163840 + po * 4;
    #pragma unroll
    for (int j = 0; j < 4; ++j) {
      iout[j] = (float)bidx[j];
      vout[j] = bval[j];
    }
    #pragma unroll
    for (int i = 0; i < 16; ++i)
      gout[i] = ((mask >> i) & 1u) ? s[i] : 0.0f;
  }
}

extern "C" void kernel_launch(void* const* d_in, const int* in_sizes, int n_in,
                              void* d_out, int out_size, void* d_ws, size_t ws_size,
                              hipStream_t stream) {
  const float* x     = (const float*)d_in[0];
  const float* femb  = (const float*)d_in[1];
  const float* noise = (const float*)d_in[2];
  const float* cw    = (const float*)d_in[3];
  const float* cb    = (const float*)d_in[4];
  const float* fw    = (const float*)d_in[5];
  float* out = (float*)d_out;
  float* freqf = (float*)d_ws;                       // 128 f32 (1 KB reserved)
  float* wT    = (float*)((char*)d_ws + 1024);       // 2 MB transposed weights

  hipLaunchKernelGGL(freq_kernel, dim3(1), dim3(128), 0, stream,
                     femb, fw, freqf, out);
  hipLaunchKernelGGL(transpose_w_kernel, dim3(512), dim3(256), 0, stream,
                     cw, wT);
  hipLaunchKernelGGL(patch_route_kernel, dim3(512), dim3(256), 0, stream,
                     x, noise, cw, cb, freqf, wT, out);
}

// Round 10
// 360.527 us; speedup vs baseline: 5.3194x; 5.3194x over previous
//
#include <hip/hip_runtime.h>

// Problem constants
#define B_ 8
#define C_ 128
#define HW_ 512
#define PS 16
#define E_ 16
#define NP 1024   // patches per batch (32x32)
#define FD 512
#define CH_STRIDE (HW_ * HW_)   // x channel stride in floats
#define LROW 260  // padded LDS row (floats); GLOAD writes first 256 (1024B)

// d_out layout (flat f32):
// [0, 131072)        gates   [B, NP, E]
// [131072, 163840)   top_k_indices as float [B, NP, 4]
// [163840, 196608)   top_k_values [B, NP, 4]
// [196608]           aux_loss (0.0f)

__global__ void freq_kernel(const float* __restrict__ femb,
                            const float* __restrict__ fw,
                            float* __restrict__ freqf,
                            float* __restrict__ out) {
    int t = threadIdx.x;
    if (t == 0) out[196608] = 0.0f;  // aux_loss, rewritten every launch
    if (t < 128) {
        int b = t >> 4, e = t & 15;
        const float* fe = femb + b * FD;
        const float* w  = fw + e * FD;
        double s = 0.0;
        for (int i = 0; i < FD; ++i)
            s = fma((double)fe[i], (double)w[i], s);
        freqf[t] = (float)s;
    }
}

#define MAC4(XF, WF)                                        \
    acc = __fadd_rn(acc, __fmul_rn((XF).x, (WF).x));        \
    acc = __fadd_rn(acc, __fmul_rn((XF).y, (WF).y));        \
    acc = __fadd_rn(acc, __fmul_rn((XF).z, (WF).z));        \
    acc = __fadd_rn(acc, __fmul_rn((XF).w, (WF).w));

// direct global -> LDS, 16B per lane; LDS dest = uniform base + lane*16
#define GLOAD_LDS(GSRC, LDST)                                                  \
  __builtin_amdgcn_global_load_lds(                                            \
      (const __attribute__((address_space(1))) void*)(GSRC),                   \
      (__attribute__((address_space(3))) void*)(LDST), 16, 0, 0)

// Strict sequential f32 mul-then-add per (patch, expert) logit in np order
// (c outer, p, q innermost) -- rounding identical to the passing R3/R5 runs.
// Structure = R5 (the measured-best 360us): x AND w staged global->LDS via
// GLOAD double buffer, counted vmcnt(8) + raw s_barrier, compiler-scheduled
// LDS consume. New vs R5: (1) odd co-resident block sleeps ~half a channel
// at entry -> the 2 blocks/CU run ANTIPHASE, so one block's MAC covers the
// other's stage/drain on every SIMD; (2) s_setprio(1) around the MAC region
// so compute-phase waves preempt staging-phase waves (T5: needs the phase
// diversity that (1) creates).
__global__ __launch_bounds__(256, 2) void patch_route_kernel(
    const float* __restrict__ x,
    const float* __restrict__ noise,
    const float* __restrict__ conv_w,
    const float* __restrict__ conv_b,
    const float* __restrict__ freqf,
    float* __restrict__ out) {

  __shared__ float xs[2][16][LROW];   // [buf][pixel row p][256 + pad]
  __shared__ float ws[2][16][LROW];   // [buf][expert e][256 + pad]
  __shared__ float slg[16][16];

  const int blk = blockIdx.x;     // 0..511
  const int b   = blk >> 6;
  const int pg  = blk & 63;       // patch group of 16
  const int t   = threadIdx.x;
  const int lp  = t >> 4;         // local patch 0..15
  const int e   = t & 15;         // expert
  const int lp16 = lp * 16;
  const int patch = pg * 16 + lp;        // 0..1023
  const int pi = pg >> 1;                // patch row
  const int wv   = t >> 6;               // wave 0..3
  const int lane = t & 63;

  // antiphase de-sync: odd blocks sleep ~3.6K cyc (~half a channel) so the
  // two co-resident blocks' barrier/MAC phases interleave instead of colliding
  if (blk & 1) {
    #pragma unroll
    for (int s = 0; s < 8; ++s) __builtin_amdgcn_s_sleep(7);
  }

  // block x base: batch b, channel 0, pixel row pi*16, col (pg&1)*256
  const float* xblk = x + (size_t)b * (C_ * CH_STRIDE)
                        + (size_t)(pi * PS) * HW_ + (pg & 1) * 256;

  // ---- stage channel 0 (8 GLOADs per wave) ----
  {
    #pragma unroll
    for (int r = 0; r < 4; ++r) {
      const int p = wv * 4 + r;
      GLOAD_LDS(xblk + p * HW_ + lane * 4, &xs[0][p][0]);
    }
    #pragma unroll
    for (int r = 0; r < 4; ++r) {
      const int ee = wv * 4 + r;
      GLOAD_LDS(conv_w + (size_t)ee * 32768 + lane * 4, &ws[0][ee][0]);
    }
  }

  float acc = 0.0f;
  for (int c = 0; c < C_; ++c) {
    const int cur = c & 1;
    if (c + 1 < C_) {
      // issue next channel's 8 loads/wave, then wait only for current's
      const int nb = cur ^ 1;
      const float* xc = xblk + (size_t)(c + 1) * CH_STRIDE;
      const float* wc = conv_w + (c + 1) * 256;
      #pragma unroll
      for (int r = 0; r < 4; ++r) {
        const int p = wv * 4 + r;
        GLOAD_LDS(xc + p * HW_ + lane * 4, &xs[nb][p][0]);
      }
      #pragma unroll
      for (int r = 0; r < 4; ++r) {
        const int ee = wv * 4 + r;
        GLOAD_LDS(wc + (size_t)ee * 32768 + lane * 4, &ws[nb][ee][0]);
      }
      asm volatile("s_waitcnt vmcnt(8)" ::: "memory");
    } else {
      asm volatile("s_waitcnt vmcnt(0)" ::: "memory");
    }
    __builtin_amdgcn_s_barrier();          // raw: no vmcnt(0) auto-drain
    __builtin_amdgcn_sched_barrier(0);

    // consume buffer `cur`: strict np-order chain (p outer, q inner);
    // compute-phase waves get scheduler priority
    __builtin_amdgcn_s_setprio(1);
    #pragma unroll
    for (int p = 0; p < 16; ++p) {
      const float4 x0 = *reinterpret_cast<const float4*>(&xs[cur][p][lp16 +  0]);
      const float4 x1 = *reinterpret_cast<const float4*>(&xs[cur][p][lp16 +  4]);
      const float4 x2 = *reinterpret_cast<const float4*>(&xs[cur][p][lp16 +  8]);
      const float4 x3 = *reinterpret_cast<const float4*>(&xs[cur][p][lp16 + 12]);
      const float4 w0 = *reinterpret_cast<const float4*>(&ws[cur][e][p * 16 +  0]);
      const float4 w1 = *reinterpret_cast<const float4*>(&ws[cur][e][p * 16 +  4]);
      const float4 w2 = *reinterpret_cast<const float4*>(&ws[cur][e][p * 16 +  8]);
      const float4 w3 = *reinterpret_cast<const float4*>(&ws[cur][e][p * 16 + 12]);
      MAC4(x0, w0);
      MAC4(x1, w1);
      MAC4(x2, w2);
      MAC4(x3, w3);
    }
    __builtin_amdgcn_s_setprio(0);

    __builtin_amdgcn_sched_barrier(0);
    __builtin_amdgcn_s_barrier();          // all waves done with `cur`
  }

  // logits, f32 adds in reference order: (+conv_b) -> (+freq) -> (+noise)
  float lg = __fadd_rn(acc, conv_b[e]);
  lg = __fadd_rn(lg, freqf[b * 16 + e]);
  lg = __fadd_rn(lg, noise[((size_t)b * NP + patch) * 16 + e]);

  slg[lp][e] = lg;
  __syncthreads();

  // ---- f32 softmax + top-4, one thread per patch (identical to round 3) ----
  if (t < 16) {
    const int pp = t;
    const int pat = pg * 16 + pp;
    float v[16];
    #pragma unroll
    for (int i = 0; i < 16; ++i) v[i] = slg[pp][i];

    float m = v[0];
    #pragma unroll
    for (int i = 1; i < 16; ++i) m = fmaxf(m, v[i]);

    float ex[16];
    #pragma unroll
    for (int i = 0; i < 16; ++i) ex[i] = expf(v[i] - m);

    // numpy pairwise-16 sum for the denominator
    float r[8];
    #pragma unroll
    for (int j = 0; j < 8; ++j) r[j] = __fadd_rn(ex[j], ex[j + 8]);
    float d0 = __fadd_rn(__fadd_rn(r[0], r[1]), __fadd_rn(r[2], r[3]));
    float d1 = __fadd_rn(__fadd_rn(r[4], r[5]), __fadd_rn(r[6], r[7]));
    float den = __fadd_rn(d0, d1);

    float s[16];
    #pragma unroll
    for (int i = 0; i < 16; ++i) s[i] = ex[i] / den;

    unsigned mask = 0;
    int bidx[4]; float bval[4];
    #pragma unroll
    for (int j = 0; j < 4; ++j) {
      int bi = 0; float bv = -1.0f;
      #pragma unroll
      for (int i = 0; i < 16; ++i) {
        if (!((mask >> i) & 1u) && s[i] > bv) { bv = s[i]; bi = i; }
      }
      mask |= 1u << bi;
      bidx[j] = bi; bval[j] = bv;
    }

    const size_t po = (size_t)b * NP + pat;
    float* gout = out + po * 16;
    float* iout = out + 131072 + po * 4;
    float* vout = out + 163840 + po * 4;
    #pragma unroll
    for (int j = 0; j < 4; ++j) {
      iout[j] = (float)bidx[j];
      vout[j] = bval[j];
    }
    #pragma unroll
    for (int i = 0; i < 16; ++i)
      gout[i] = ((mask >> i) & 1u) ? s[i] : 0.0f;
  }
}

extern "C" void kernel_launch(void* const* d_in, const int* in_sizes, int n_in,
                              void* d_out, int out_size, void* d_ws, size_t ws_size,
                              hipStream_t stream) {
  const float* x     = (const float*)d_in[0];
  const float* femb  = (const float*)d_in[1];
  const float* noise = (const float*)d_in[2];
  const float* cw    = (const float*)d_in[3];
  const float* cb    = (const float*)d_in[4];
  const float* fw    = (const float*)d_in[5];
  float* out = (float*)d_out;
  float* freqf = (float*)d_ws;   // 128 floats

  hipLaunchKernelGGL(freq_kernel, dim3(1), dim3(128), 0, stream,
                     femb, fw, freqf, out);
  hipLaunchKernelGGL(patch_route_kernel, dim3(512), dim3(256), 0, stream,
                     x, noise, cw, cb, freqf, out);
}